// Round 16
// baseline (372.336 us; speedup 1.0000x reference)
//
#include <hip/hip_runtime.h>
#include <hip/hip_bf16.h>
#include <math.h>

#define B_SZ 4
#define C_SZ 512
#define N_SZ 4096
#define D_SZ 64
#define SHIFT 60.0f

typedef __attribute__((ext_vector_type(4))) float f32x4;
typedef __attribute__((ext_vector_type(8))) short bf16x8;
typedef __attribute__((ext_vector_type(4))) short s16x4;
typedef __attribute__((ext_vector_type(8))) _Float16 f16x8;

// fp32 -> bf16 RNE via native convert
__device__ __forceinline__ short f2bf(float x) {
    return (short)__bfloat16_as_ushort(__float2bfloat16(x));
}

__device__ __forceinline__ bf16x8 pack8(float4 a, float4 b) {
    bf16x8 r;
    r[0] = f2bf(a.x); r[1] = f2bf(a.y); r[2] = f2bf(a.z); r[3] = f2bf(a.w);
    r[4] = f2bf(b.x); r[5] = f2bf(b.y); r[6] = f2bf(b.z); r[7] = f2bf(b.w);
    return r;
}

// fp32x8 -> fp16x8 (RNE)
__device__ __forceinline__ f16x8 pack8h(float4 a, float4 b) {
    f16x8 r;
    r[0] = (_Float16)a.x; r[1] = (_Float16)a.y; r[2] = (_Float16)a.z; r[3] = (_Float16)a.w;
    r[4] = (_Float16)b.x; r[5] = (_Float16)b.y; r[6] = (_Float16)b.z; r[7] = (_Float16)b.w;
    return r;
}

// ---------------------------------------------------------------------------
// Pre-pass: a fp32 -> bf16 (PV operand)
// ---------------------------------------------------------------------------
__global__ __launch_bounds__(256) void conv_a_kernel(
    const float* __restrict__ amat, short* __restrict__ abf)
{
    size_t i = ((size_t)blockIdx.x * 256 + threadIdx.x) * 8;
    float4 a0 = ((const float4*)(amat + i))[0];
    float4 a1 = ((const float4*)(amat + i))[1];
    *(bf16x8*)(abf + i) = pack8(a0, a1);
}

// Pre-pass: c fp32 -> fp16 (QK operand)
__global__ __launch_bounds__(256) void conv_c_kernel(
    const float* __restrict__ cmat, _Float16* __restrict__ ch)
{
    size_t i = ((size_t)blockIdx.x * 256 + threadIdx.x) * 8;
    float4 c0 = ((const float4*)(cmat + i))[0];
    float4 c1 = ((const float4*)(cmat + i))[1];
    *(f16x8*)(ch + i) = pack8h(c0, c1);
}

// ---------------------------------------------------------------------------
// Fused pass (pv10): BARRIER-FREE. Each wave is self-contained:
//   wave (wm = w&1, wc = w>>1) owns 128ch x 32m of the block's 256ch x 64m.
//   Per 64-n chunk: swapped QK (mfma(K,Q)) for its OWN 32 m-rows, all 64 n
//   (16 MFMA; x2 QK duplication across wc waves -- +20% MFMA, no sync);
//   P -> wave-PRIVATE LDS (2 buffers; same-wave DS write->read, in-order
//   DS pipe + compiler lgkmcnt, NO __syncthreads in the whole main loop);
//   PV (32 MFMA) with af direct from L2 (L1-shared between wm pair).
//   L is wave-local: per-lane psum + 2 end shuffles. No cross-wave anything.
// ---------------------------------------------------------------------------
__global__ __launch_bounds__(256, 2) void pv10_kernel(
    const float* __restrict__ amat, const float* __restrict__ bmat,
    const short* __restrict__ abf, const _Float16* __restrict__ chm,
    float* __restrict__ out)
{
    const int t = threadIdx.x;
    const int lane = t & 63;
    const int l15 = lane & 15;
    const int g = lane >> 4;
    const int w = t >> 6;
    const int wm = w & 1;    // m half (32 rows)
    const int wc = w >> 1;   // ch half (128 ch)

    const int bid = blockIdx.x;
    const int slice = bid & 7;         // -> XCD via dispatch round-robin
    const int gm0 = (bid >> 3) * 64;   // m-tile
    const int gc0 = (slice & 1) * 256; // ch half (block)
    const int bz = slice >> 1;         // batch

    const int mb = gm0 + wm * 32;      // this wave's 32 m-rows
    const int cb = gc0 + wc * 128;     // this wave's 128 channels

    // wave-private P: [wave][buf][32 m][72 n-pitch]
    __shared__ __align__(16) short smp[4][2][32 * 72];
    short* const pw_base = &smp[w][0][0];

    // Q fragments (B-operand of swapped QK): rows mb + mf2*16 + l15
    f16x8 qf[2][2];
#pragma unroll
    for (int mf2 = 0; mf2 < 2; ++mf2)
#pragma unroll
        for (int kf = 0; kf < 2; ++kf) {
            const float* qp = bmat + ((size_t)bz * N_SZ + mb + mf2 * 16 + l15) * D_SZ
                              + kf * 32 + g * 8;
            float4 q0 = ((const float4*)qp)[0];
            float4 q1 = ((const float4*)qp)[1];
            qf[mf2][kf] = pack8h(q0, q1);
        }

    f32x4 acc[8][2];
#pragma unroll
    for (int i = 0; i < 8; ++i)
#pragma unroll
        for (int j = 0; j < 2; ++j)
            acc[i][j] = (f32x4){0.f, 0.f, 0.f, 0.f};

    float psum[2] = {0.f, 0.f};

    // K base (A-operand): row l15 within n-strip, d-octet g*8
    const _Float16* kb = chm + ((size_t)bz * N_SZ + l15) * D_SZ + g * 8;
    // af base (A-operand): ch row cb + l15, n-octet g*8
    const short* ab = abf + ((size_t)bz * C_SZ + cb + l15) * N_SZ + g * 8;

    for (int k = 0; k < 64; ++k) {
        const int n0 = k * 64;
        short* const pbuf = pw_base + (k & 1) * (32 * 72);

        // ---- QK: K loads + 16 MFMA + exp + P write (wave-private) ----
        f16x8 kA[4][2];
#pragma unroll
        for (int nf = 0; nf < 4; ++nf) {
            const _Float16* kp = kb + (size_t)(n0 + nf * 16) * D_SZ;
            kA[nf][0] = *(const f16x8*)(kp);
            kA[nf][1] = *(const f16x8*)(kp + 32);
        }
#pragma unroll
        for (int mf2 = 0; mf2 < 2; ++mf2)
#pragma unroll
            for (int nf = 0; nf < 4; ++nf) {
                f32x4 s = {0.f, 0.f, 0.f, 0.f};
                s = __builtin_amdgcn_mfma_f32_16x16x32_f16(kA[nf][0], qf[mf2][0], s, 0, 0, 0);
                s = __builtin_amdgcn_mfma_f32_16x16x32_f16(kA[nf][1], qf[mf2][1], s, 0, 0, 0);
                // lane: P[n = n0 + nf*16 + g*4 + r][m = mb + mf2*16 + l15]
                float p0 = __expf(s[0] - SHIFT);
                float p1 = __expf(s[1] - SHIFT);
                float p2 = __expf(s[2] - SHIFT);
                float p3 = __expf(s[3] - SHIFT);
                psum[mf2] += (p0 + p1) + (p2 + p3);
                s16x4 pv;
                pv[0] = f2bf(p0); pv[1] = f2bf(p1); pv[2] = f2bf(p2); pv[3] = f2bf(p3);
                *(s16x4*)&pbuf[(mf2 * 16 + l15) * 72 + nf * 16 + g * 4] = pv;
            }

        // ---- P read-back as PV B-frags (same wave; DS-pipe ordered) ----
        bf16x8 pf[2][2];
#pragma unroll
        for (int mf2 = 0; mf2 < 2; ++mf2)
#pragma unroll
            for (int kf = 0; kf < 2; ++kf)
                pf[mf2][kf] = *(const bf16x8*)&pbuf[(mf2 * 16 + l15) * 72 + kf * 32 + g * 8];

        // ---- PV: 16 af loads, 32 MFMA ----
#pragma unroll
        for (int chf = 0; chf < 8; ++chf)
#pragma unroll
            for (int kf = 0; kf < 2; ++kf) {
                bf16x8 af = *(const bf16x8*)(ab + (size_t)chf * 16 * N_SZ + n0 + kf * 32);
                acc[chf][0] = __builtin_amdgcn_mfma_f32_16x16x32_bf16(af, pf[0][kf], acc[chf][0], 0, 0, 0);
                acc[chf][1] = __builtin_amdgcn_mfma_f32_16x16x32_bf16(af, pf[1][kf], acc[chf][1], 0, 0, 0);
            }
    }

    // L: wave-local reduce over the 4 g-groups (same l15 = same m)
    float ri[2];
#pragma unroll
    for (int mf2 = 0; mf2 < 2; ++mf2) {
        float v = psum[mf2];
        v += __shfl_xor(v, 16, 64);
        v += __shfl_xor(v, 32, 64);
        ri[mf2] = 1.0f / v;
    }

    // epilogue: out = acc / L + a
#pragma unroll
    for (int chf = 0; chf < 8; ++chf)
#pragma unroll
        for (int mf2 = 0; mf2 < 2; ++mf2) {
            const int m = mb + mf2 * 16 + l15;
#pragma unroll
            for (int r = 0; r < 4; ++r) {
                const int ch = cb + chf * 16 + g * 4 + r;
                size_t o = ((size_t)bz * C_SZ + ch) * N_SZ + m;
                out[o] = acc[chf][mf2][r] * ri[mf2] + amat[o];
            }
        }
}

extern "C" void kernel_launch(void* const* d_in, const int* in_sizes, int n_in,
                              void* d_out, int out_size, void* d_ws, size_t ws_size,
                              hipStream_t stream) {
    const float* a = (const float*)d_in[0];
    const float* b = (const float*)d_in[1];
    const float* c = (const float*)d_in[2];
    float* out = (float*)d_out;

    // ws layout: abf (bf16, 8 MB) | c fp16 (2 MB)
    const size_t abf_b = (size_t)B_SZ * C_SZ * N_SZ * 2;

    short* abf = (short*)d_ws;
    _Float16* chm = (_Float16*)((char*)d_ws + abf_b);

    conv_a_kernel<<<dim3((B_SZ * C_SZ * N_SZ) / (256 * 8)), 256, 0, stream>>>(a, abf);
    conv_c_kernel<<<dim3((B_SZ * N_SZ * D_SZ) / (256 * 8)), 256, 0, stream>>>(c, chm);
    pv10_kernel<<<dim3(512), 256, 0, stream>>>(a, b, abf, chm, out);
}

// Round 17
// 188.940 us; speedup vs baseline: 1.9707x; 1.9707x over previous
//
#include <hip/hip_runtime.h>
#include <hip/hip_bf16.h>
#include <math.h>

#define B_SZ 4
#define C_SZ 512
#define N_SZ 4096
#define D_SZ 64
#define SHIFT 60.0f

typedef __attribute__((ext_vector_type(4))) float f32x4;
typedef __attribute__((ext_vector_type(8))) short bf16x8;
typedef __attribute__((ext_vector_type(4))) short s16x4;
typedef __attribute__((ext_vector_type(8))) _Float16 f16x8;

// fp32 -> bf16 RNE via native convert
__device__ __forceinline__ short f2bf(float x) {
    return (short)__bfloat16_as_ushort(__float2bfloat16(x));
}

__device__ __forceinline__ bf16x8 pack8(float4 a, float4 b) {
    bf16x8 r;
    r[0] = f2bf(a.x); r[1] = f2bf(a.y); r[2] = f2bf(a.z); r[3] = f2bf(a.w);
    r[4] = f2bf(b.x); r[5] = f2bf(b.y); r[6] = f2bf(b.z); r[7] = f2bf(b.w);
    return r;
}

// fp32x8 -> fp16x8 (RNE)
__device__ __forceinline__ f16x8 pack8h(float4 a, float4 b) {
    f16x8 r;
    r[0] = (_Float16)a.x; r[1] = (_Float16)a.y; r[2] = (_Float16)a.z; r[3] = (_Float16)a.w;
    r[4] = (_Float16)b.x; r[5] = (_Float16)b.y; r[6] = (_Float16)b.z; r[7] = (_Float16)b.w;
    return r;
}

// ---------------------------------------------------------------------------
// Pre-pass: a fp32 -> bf16 (PV operand)
// ---------------------------------------------------------------------------
__global__ __launch_bounds__(256) void conv_a_kernel(
    const float* __restrict__ amat, short* __restrict__ abf)
{
    size_t i = ((size_t)blockIdx.x * 256 + threadIdx.x) * 8;
    float4 a0 = ((const float4*)(amat + i))[0];
    float4 a1 = ((const float4*)(amat + i))[1];
    *(bf16x8*)(abf + i) = pack8(a0, a1);
}

// Pre-pass: c fp32 -> fp16 (QK operand)
__global__ __launch_bounds__(256) void conv_c_kernel(
    const float* __restrict__ cmat, _Float16* __restrict__ ch)
{
    size_t i = ((size_t)blockIdx.x * 256 + threadIdx.x) * 8;
    float4 c0 = ((const float4*)(cmat + i))[0];
    float4 c1 = ((const float4*)(cmat + i))[1];
    *(f16x8*)(ch + i) = pack8h(c0, c1);
}

// ---------------------------------------------------------------------------
// Fused pass (pv11): R15 (swapped QK, VGPR 80) + R13's static-named register
// prefetch, now WITH headroom (R13 spilled at the 128 cap; here ~165 VGPR).
//   - af (PV A-operand) double-buffered one chunk ahead (afr0/afr1, 64 VGPR)
//   - K fp16 frags double-buffered one segment ahead (krr0/krr1, 16 VGPR)
//   - swapped QK mfma(K,Q) -> C[n][m]: b64 P-stores, wave-local-ish L sums
//   - 4 P LDS buffers, one barrier per 128-n segment
// ---------------------------------------------------------------------------
__global__ __launch_bounds__(256, 2) void pv11_kernel(
    const float* __restrict__ amat, const float* __restrict__ bmat,
    const short* __restrict__ abf, const _Float16* __restrict__ chm,
    float* __restrict__ out)
{
    const int t = threadIdx.x;
    const int lane = t & 63;
    const int l15 = lane & 15;
    const int lg = lane >> 4;
    const int w = t >> 6;

    const int bid = blockIdx.x;
    const int slice = bid & 7;         // -> XCD via dispatch round-robin
    const int gm0 = (bid >> 3) * 64;   // m-tile
    const int gc0 = (slice & 1) * 256; // ch half
    const int bz = slice >> 1;         // batch

    __shared__ __align__(16) short smp[4][64 * 72];  // P [m][n], 4 buffers
    __shared__ float ldsL4[4][64];

    // Q fragments (B-operand of swapped QK)
    f16x8 qf[4][2];
#pragma unroll
    for (int mf = 0; mf < 4; ++mf)
#pragma unroll
        for (int kf = 0; kf < 2; ++kf) {
            const float* qp = bmat + ((size_t)bz * N_SZ + gm0 + mf * 16 + l15) * D_SZ
                              + kf * 32 + lg * 8;
            float4 q0 = ((const float4*)qp)[0];
            float4 q1 = ((const float4*)qp)[1];
            qf[mf][kf] = pack8h(q0, q1);
        }

    f32x4 acc[4][4];
#pragma unroll
    for (int i = 0; i < 4; ++i)
#pragma unroll
        for (int j = 0; j < 4; ++j)
            acc[i][j] = (f32x4){0.f, 0.f, 0.f, 0.f};

    float psum[4] = {0.f, 0.f, 0.f, 0.f};

    // K-fragment base (MFMA A): c row (w*16 + l15), d-octet lg*8
    const _Float16* kb = chm + ((size_t)bz * N_SZ + w * 16 + l15) * D_SZ + lg * 8;
    // af base (PV A): a row (gc0 + w*64 + l15), n-octet lg*8
    const short* ab = abf + ((size_t)bz * C_SZ + gc0 + w * 64 + l15) * N_SZ + lg * 8;

    // prefetch registers: NAMED buffers only (rule #20)
    bf16x8 afr0[4][2], afr1[4][2];   // [chf][kf], one 64-n chunk each
    f16x8 krr0[2][2], krr1[2][2];    // [chunk-in-segment][half]

    auto LOADAF = [&](int n0, bf16x8 (&dst)[4][2]) {
#pragma unroll
        for (int chf = 0; chf < 4; ++chf)
#pragma unroll
            for (int kf = 0; kf < 2; ++kf)
                dst[chf][kf] =
                    *(const bf16x8*)(ab + (size_t)chf * 16 * N_SZ + n0 + kf * 32);
    };
    auto LOADK = [&](int n0, f16x8 (&dst)[2][2]) {
#pragma unroll
        for (int ck = 0; ck < 2; ++ck) {
            const _Float16* kp = kb + (size_t)(n0 + ck * 64) * D_SZ;
            dst[ck][0] = *(const f16x8*)(kp);
            dst[ck][1] = *(const f16x8*)(kp + 32);
        }
    };

    // swapped QK: K (A-op) from regs -> P into smp[pbuf] as b64 stores
    auto QK = [&](int pbuf, f16x8 k0, f16x8 k1) {
#pragma unroll
        for (int mf = 0; mf < 4; ++mf) {
            f32x4 s = {0.f, 0.f, 0.f, 0.f};
            s = __builtin_amdgcn_mfma_f32_16x16x32_f16(k0, qf[mf][0], s, 0, 0, 0);
            s = __builtin_amdgcn_mfma_f32_16x16x32_f16(k1, qf[mf][1], s, 0, 0, 0);
            // lane: P[n = w*16 + lg*4 + r][m = mf*16 + l15]
            float p0 = __expf(s[0] - SHIFT);
            float p1 = __expf(s[1] - SHIFT);
            float p2 = __expf(s[2] - SHIFT);
            float p3 = __expf(s[3] - SHIFT);
            psum[mf] += (p0 + p1) + (p2 + p3);
            s16x4 pw;
            pw[0] = f2bf(p0); pw[1] = f2bf(p1); pw[2] = f2bf(p2); pw[3] = f2bf(p3);
            *(s16x4*)&smp[pbuf][(mf * 16 + l15) * 72 + w * 16 + lg * 4] = pw;
        }
    };

    // PV: af from named reg buffer, P from smp[pbuf]
    auto PV = [&](int pbuf, bf16x8 (&af)[4][2]) {
#pragma unroll
        for (int kf = 0; kf < 2; ++kf) {
            bf16x8 pf[4];
#pragma unroll
            for (int mf = 0; mf < 4; ++mf)
                pf[mf] = *(const bf16x8*)&smp[pbuf][(mf * 16 + l15) * 72 + kf * 32 + lg * 8];
#pragma unroll
            for (int chf = 0; chf < 4; ++chf)
#pragma unroll
                for (int mf = 0; mf < 4; ++mf)
                    acc[chf][mf] = __builtin_amdgcn_mfma_f32_16x16x32_bf16(
                        af[chf][kf], pf[mf], acc[chf][mf], 0, 0, 0);
        }
    };

    // one segment: PV chunks 2s,2s+1 (af prefetched); QK chunks 2s+2,2s+3;
    // K prefetch for 2s+4,2s+5 (unless last).
    auto SEG = [&](int s, f16x8 (&kq)[2][2], f16x8 (&kn)[2][2],
                   int p0, int p1, int p2, int p3, bool loadk) {
        __syncthreads();
        LOADAF(s * 128 + 64, afr1);
        PV(p0, afr0);
        LOADAF(s * 128 + 128, afr0);
        PV(p1, afr1);
        QK(p2, kq[0][0], kq[0][1]);
        QK(p3, kq[1][0], kq[1][1]);
        if (loadk) LOADK(s * 128 + 256, kn);
    };

    // prologue
    LOADK(0, krr0);                        // chunks 0,1
    QK(0, krr0[0][0], krr0[0][1]);         // chunk 0 -> pbuf 0
    QK(1, krr0[1][0], krr0[1][1]);         // chunk 1 -> pbuf 1
    LOADK(128, krr1);                      // chunks 2,3
    LOADAF(0, afr0);                       // chunk 0

    for (int sp = 0; sp < 15; ++sp) {
        const int s = 2 * sp;
        SEG(s,     krr1, krr0, 0, 1, 2, 3, true);   // even s
        SEG(s + 1, krr0, krr1, 2, 3, 0, 1, true);   // odd s
    }
    SEG(30, krr1, krr0, 0, 1, 2, 3, false);

    __syncthreads();
    LOADAF(4032, afr1);                    // chunk 63
    PV(2, afr0);                           // chunk 62
    PV(3, afr1);                           // chunk 63

    // L reduction: sum over lg groups (xor 16, 32), then cross-wave via LDS.
#pragma unroll
    for (int mf = 0; mf < 4; ++mf) {
        float v = psum[mf];
        v += __shfl_xor(v, 16, 64);
        v += __shfl_xor(v, 32, 64);
        if (lg == 0) ldsL4[w][mf * 16 + l15] = v;
    }
    __syncthreads();

    float ri[4];
#pragma unroll
    for (int mf = 0; mf < 4; ++mf) {
        int m = mf * 16 + l15;
        ri[mf] = 1.0f / (ldsL4[0][m] + ldsL4[1][m] + ldsL4[2][m] + ldsL4[3][m]);
    }

    // epilogue: out = acc / L + a
#pragma unroll
    for (int chf = 0; chf < 4; ++chf)
#pragma unroll
        for (int mf = 0; mf < 4; ++mf) {
            const int m = gm0 + mf * 16 + l15;
#pragma unroll
            for (int r = 0; r < 4; ++r) {
                const int ch = gc0 + w * 64 + chf * 16 + lg * 4 + r;
                size_t o = ((size_t)bz * C_SZ + ch) * N_SZ + m;
                out[o] = acc[chf][mf][r] * ri[mf] + amat[o];
            }
        }
}

extern "C" void kernel_launch(void* const* d_in, const int* in_sizes, int n_in,
                              void* d_out, int out_size, void* d_ws, size_t ws_size,
                              hipStream_t stream) {
    const float* a = (const float*)d_in[0];
    const float* b = (const float*)d_in[1];
    const float* c = (const float*)d_in[2];
    float* out = (float*)d_out;

    // ws layout: abf (bf16, 8 MB) | c fp16 (2 MB)
    const size_t abf_b = (size_t)B_SZ * C_SZ * N_SZ * 2;

    short* abf = (short*)d_ws;
    _Float16* chm = (_Float16*)((char*)d_ws + abf_b);

    conv_a_kernel<<<dim3((B_SZ * C_SZ * N_SZ) / (256 * 8)), 256, 0, stream>>>(a, abf);
    conv_c_kernel<<<dim3((B_SZ * N_SZ * D_SZ) / (256 * 8)), 256, 0, stream>>>(c, chm);
    pv11_kernel<<<dim3(512), 256, 0, stream>>>(a, b, abf, chm, out);
}